// Round 10
// baseline (380.298 us; speedup 1.0000x reference)
//
#include <hip/hip_runtime.h>
#include <math.h>
#include <stdint.h>

// Problem constants
#define BB    32
#define CIN   64
#define HH    32
#define WW    32
#define COUT  128
#define PP    1024      // HH*WW
#define OTILE 8         // output channels per block
#define PTILE 256       // pixels per block (4 waves x 64 px = 8 rows)
#define NPAD  16        // floats per (o,c) group (9 real + 7 pads)
#define CHUNK 128       // dwords per (c, o-tile) permuted theta chunk
#define TABN  160       // f-table knots
#define TROW  36        // tile row stride (34 cols + 2 slack)
#define TWSZ  148       // per-wave tile dwords (4*36 + dump + pad)

// Log2 domain: Z = (x - theta)*SCALEE. Table coord u = 8Z + 24 = x*MSC8 + thp,
// thp = 24 - theta*MSC8.
static constexpr float MSC8     = 153.88747102815611f;   // inv_denom*log2(e)*8
static constexpr float M2N      = 0.26359713811572677f;  // 2^-SBITS = e^-shift
static constexpr float OUTSCALE = 2.7025482032898827e-05f; // ALPHA*R*ln2^2
static constexpr float ZLO      = -3.0f;
static constexpr float TABH     = 0.125f;
static constexpr float IDXBIAS  = 24.0f;                 // -ZLO/h
static constexpr float CUTBIAS  = 4.0f;                  // 24 - 8*ZCUT, ZCUT = 2.5

// ---------------- P0: prescale, koff-stuff, sort desc, permuted store -------
// Permuted chunk layout per (c, o-tile): float (g,j) lives at dword
//   (g&3)*32 + (g>>2)*16 + j
// so the main kernel loads reg r = dwords [r*32 .. r*32+31] (lane = l&31) and a
// body's theta is readlane(tb[g&3], (g>>2)*16 + j)  — reg idx compile-time.
__global__ __launch_bounds__(256) void sort_theta_kernel(
    const float* __restrict__ theta, float* __restrict__ ws)
{
    int gid = blockIdx.x * 256 + threadIdx.x;   // o*CIN + c (theta layout)
    if (gid >= COUT * CIN) return;
    int o = gid >> 6, c = gid & 63;
    const float* tg = theta + (size_t)gid * 9;
    float v[NPAD];
#pragma unroll
    for (int k = 0; k < 9; ++k) {
        float thp = fmaf(tg[k], -MSC8, IDXBIAS);
        int dy = k / 3, dx = k - 3 * dy;
        uint32_t koff = (uint32_t)(dy * TROW + dx);      // {0,1,2,36,37,38,72,73,74}
        v[k] = __uint_as_float((__float_as_uint(thp) & ~0x7Fu) | koff);
    }
    for (int i = 1; i < 9; ++i) {               // insertion sort DESCENDING
        float key = v[i];
        int j = i - 1;
        while (j >= 0 && v[j] < key) { v[j + 1] = v[j]; --j; }
        v[j + 1] = key;
    }
    float pad = __uint_as_float(__float_as_uint(-1e30f) & ~0x7Fu);  // inactive, koff=0
#pragma unroll
    for (int j = 9; j < NPAD; ++j) v[j] = pad;
    int g = o & 7, oc = o >> 3;
    float* og = ws + (size_t)(c * 16 + oc) * CHUNK + (g & 3) * 32 + ((g >> 2) << 4);
#pragma unroll
    for (int j = 0; j < NPAD; ++j) og[j] = v[j];
}

// ---------------- P1: per-(b, band, c) cut in thp units ----------------
__global__ __launch_bounds__(256) void bandcut_kernel(
    const float* __restrict__ x, float* __restrict__ bandcut)
{
    int t  = threadIdx.x;
    int bc = blockIdx.x;            // b*CIN + c
    const float4* xp = (const float4*)(x + (size_t)bc * PP);
    float4 v = xp[t];               // thread t: row t>>3, cols 4(t&7)..+3
    float m = fmaxf(fmaxf(v.x, v.y), fmaxf(v.z, v.w));
    m = fmaxf(m, __shfl_xor(m, 1));
    m = fmaxf(m, __shfl_xor(m, 2));
    m = fmaxf(m, __shfl_xor(m, 4));   // 8 threads of a row hold rowmax
    __shared__ float rmax[32];
    if ((t & 7) == 0) rmax[t >> 3] = m;
    __syncthreads();
    if (t < 16) {
        int r0 = max(2 * t - 1, 0), r3 = min(2 * t + 2, 31);
        float mm = rmax[r0];
        for (int r = r0 + 1; r <= r3; ++r) mm = fmaxf(mm, rmax[r]);
        mm = fmaxf(mm, 0.0f);         // zero-pad contributes xi = 0
        int b = bc >> 6, c = bc & 63;
        bandcut[((b * 16 + t) << 6) + c] = fmaf(mm, -MSC8, CUTBIAS);
    }
}

// ---------------- main kernel ----------------
__global__ __launch_bounds__(256) void nlconv_kernel(
    const float* __restrict__ x,        // [B, CIN, 32, 32]
    const float* __restrict__ wst,      // permuted sorted thp chunks
    const float* __restrict__ wcut,     // cutp [b][band][c]
    float* __restrict__ out)            // [B, COUT, 32, 32]
{
    __shared__ float  sxi[4 * TWSZ];    // per-wave 4x36 halo tiles + dump, 2368 B
    __shared__ float2 ftab[TABN];       // coefficient table (c0, c1), 1280 B

    const int t  = threadIdx.x;
    const int b  = blockIdx.x;
    const int pt = blockIdx.y;
    const int ot = blockIdx.z;
    const int w  = t >> 6;
    const int l  = t & 63;
    const int l32 = l & 31;
    const int o0 = ot * OTILE;
    const int band = pt * 4 + w;
    const int rl = l >> 5, col = l & 31;

    // build the coefficient table in-kernel (fp32; err ~1e-5 f-units, negligible)
    if (t < TABN) {
        float Z0 = ZLO + TABH * (float)t;
        auto fe = [](float Z) {
            float E = exp2f(Z);
            float a = log2f(1.0f + E);
            float bq = log2f(fmaf(E, M2N, 1.0f));
            return a * a - bq * bq;
        };
        float y0 = fe(Z0), y1 = fe(Z0 + TABH);
        float c1 = y1 - y0;                       // per-u slope; i=158 segment
        ftab[t] = make_float2(fmaf(-(float)t, c1, y0), c1);  // extrapolates tail
    }

    // per-lane staging map: 3 entries e = l, l+64, l+128 over the 144-dword tile
    const int wbase = w * TWSZ;
    int   gofs[3];   // dword offset within a channel's 1024-px image
    float msc[3];    // MSC8 or 0 (halo/invalid)
    int   laddr[3];  // dword index into sxi
#pragma unroll
    for (int i = 0; i < 3; ++i) {
        int e  = l + 64 * i;
        bool valid = (e < 144);
        int ec = valid ? e : 144;           // dump slot for invalid third entries
        int r  = ec / TROW;
        int tc = ec - r * TROW;
        int grow = band * 2 - 1 + r;
        int gcol = tc - 1;
        bool inter = valid && (grow >= 0) && (grow < HH) && (gcol >= 0) && (gcol < WW) && (r < 4);
        gofs[i]  = (min(max(grow, 0), HH - 1) << 5) + min(max(gcol, 0), WW - 1);
        msc[i]   = inter ? MSC8 : 0.0f;
        laddr[i] = wbase + min(ec, TWSZ - 1);
    }

    // this wave's 64 channel cuts: lane c holds cutp[c]
    const float vcut = wcut[(size_t)((b * 16 + band) << 6) + l];

    // spread gather offsets for the ballot count (permuted chunk coords)
    const int g1 = l >> 3, j1 = l & 7, g2 = l & 7;
    const int spA = (g1 & 3) * 32 + ((g1 >> 2) << 4) + j1;   // j = l&7 of group l>>3
    const int spB = (g2 & 3) * 32 + ((g2 >> 2) << 4) + 8;    // j = 8 of group l&7

    const float* xc0 = x + (size_t)b * CIN * PP;
    const float* wch = wst + (size_t)ot * CHUNK;   // + c*16*CHUNK
    const int xb = wbase + rl * TROW + col;        // body x base (dword)

    float acc[OTILE];
#pragma unroll
    for (int i = 0; i < OTILE; ++i) acc[i] = 0.0f;

    // prologue: tile(0); xv <- c=1; theta block + spreads for c=0 (all VMEM)
    float xv[3];
#pragma unroll
    for (int i = 0; i < 3; ++i) xv[i] = xc0[gofs[i]] * msc[i];
#pragma unroll
    for (int i = 0; i < 3; ++i) sxi[laddr[i]] = xv[i];
#pragma unroll
    for (int i = 0; i < 3; ++i) xv[i] = xc0[PP + gofs[i]] * msc[i];

    float f1 = wch[spA], f2 = wch[spB];
    float tb0 = wch[l32], tb1 = wch[32 + l32], tb2 = wch[64 + l32], tb3 = wch[96 + l32];

    __syncthreads();   // ftab ready (tiles are wave-private)

    for (int c = 0; c < CIN; ++c) {
        const float cutp = __uint_as_float(
            (uint32_t)__builtin_amdgcn_readlane((int)__float_as_uint(vcut), c));
        unsigned long long mA = __ballot(f1 > cutp);
        unsigned long long mB = __ballot(f2 > cutp);

        // prefetch next channel's theta block + spreads (VMEM, consumed next iter)
        const float* wn = wch + (size_t)min(c + 1, CIN - 1) * (16 * CHUNK);
        float nf1 = wn[spA], nf2 = wn[spB];
        float nb0 = wn[l32], nb1 = wn[32 + l32], nb2 = wn[64 + l32], nb3 = wn[96 + l32];

#pragma unroll
        for (int g = 0; g < 8; ++g) {
            int cnt = (int)__popcll(mA & (0xFFull << (8 * g)))
                    + (int)((mB >> g) & 1ull);
            int np = (cnt + 3) >> 2;           // quad iterations (<=3)
            asm volatile("" : "+s"(np));       // opaque: loop stays a real loop
            const int slb = (g >> 2) << 4;     // lane base for this group's thetas
            const uint32_t tbg = __float_as_uint(
                (g & 3) == 0 ? tb0 : (g & 3) == 1 ? tb1 : (g & 3) == 2 ? tb2 : tb3);
            float a = acc[g];
#pragma unroll 1
            for (int j = 0; j < np; ++j) {
                int lb = slb + 4 * j;
                // theta via readlane: no memory op, lane idx uniform, reg idx static
                float th0 = __uint_as_float((uint32_t)__builtin_amdgcn_readlane((int)tbg, lb + 0));
                float th1 = __uint_as_float((uint32_t)__builtin_amdgcn_readlane((int)tbg, lb + 1));
                float th2 = __uint_as_float((uint32_t)__builtin_amdgcn_readlane((int)tbg, lb + 2));
                float th3 = __uint_as_float((uint32_t)__builtin_amdgcn_readlane((int)tbg, lb + 3));
                float xa0 = sxi[xb + (int)(__float_as_uint(th0) & 0x7Fu)];
                float xa1 = sxi[xb + (int)(__float_as_uint(th1) & 0x7Fu)];
                float xa2 = sxi[xb + (int)(__float_as_uint(th2) & 0x7Fu)];
                float xa3 = sxi[xb + (int)(__float_as_uint(th3) & 0x7Fu)];
                float u0 = fmaxf(xa0 + th0, 0.0f);   // pads: th=-1e30 -> u=0 -> ~f(-3)~0
                float u1 = fmaxf(xa1 + th1, 0.0f);
                float u2 = fmaxf(xa2 + th2, 0.0f);
                float u3 = fmaxf(xa3 + th3, 0.0f);
                int i0 = min((int)u0, TABN - 2);     // i=158 segment extrapolates tail
                int i1 = min((int)u1, TABN - 2);
                int i2 = min((int)u2, TABN - 2);
                int i3 = min((int)u3, TABN - 2);
                float2 c0 = ftab[i0];
                float2 c1 = ftab[i1];
                float2 c2 = ftab[i2];
                float2 c3 = ftab[i3];
                float t0 = fmaf(c0.y, u0, c0.x);
                float t1 = fmaf(c1.y, u1, c1.x);
                float t2 = fmaf(c2.y, u2, c2.x);
                float t3 = fmaf(c3.y, u3, c3.x);
                a += (t0 + t1) + (t2 + t3);          // tree sum, short dep chain
            }
            acc[g] = a;
        }

        // rotate prefetched theta regs; stage tile(c+1); prefetch xv(c+2)
        f1 = nf1; f2 = nf2;
        tb0 = nb0; tb1 = nb1; tb2 = nb2; tb3 = nb3;
#pragma unroll
        for (int i = 0; i < 3; ++i) sxi[laddr[i]] = xv[i];
        {
            int c2 = min(c + 2, CIN - 1);
            const float* xcn = xc0 + (size_t)c2 * PP;
#pragma unroll
            for (int i = 0; i < 3; ++i) xv[i] = xcn[gofs[i]] * msc[i];
        }
    }

    float* ob = out + ((size_t)b * COUT + o0) * PP + pt * PTILE + t;
#pragma unroll
    for (int o = 0; o < OTILE; ++o) {
        float v = acc[o] * OUTSCALE;
        v = fminf(fmaxf(v, 0.0f), 9.0f);
        ob[(size_t)o * PP] = v;
    }
}

extern "C" void kernel_launch(void* const* d_in, const int* in_sizes, int n_in,
                              void* d_out, int out_size, void* d_ws, size_t ws_size,
                              hipStream_t stream) {
    const float* x     = (const float*)d_in[0];  // [32,64,32,32]
    const float* theta = (const float*)d_in[1];  // [128,64,3,3]
    float* out         = (float*)d_out;          // [32,128,32,32]

    float* ws_theta = (float*)d_ws;                               // 524,288 B
    float* ws_cut   = ws_theta + (size_t)CIN * 16 * CHUNK;        // 131,072 B

    sort_theta_kernel<<<dim3((COUT * CIN + 255) / 256), dim3(256), 0, stream>>>(theta, ws_theta);
    bandcut_kernel<<<dim3(BB * CIN), dim3(256), 0, stream>>>(x, ws_cut);

    dim3 grid(BB, PP / PTILE, COUT / OTILE);     // 32 x 4 x 16 = 2048 blocks
    nlconv_kernel<<<grid, dim3(256), 0, stream>>>(x, ws_theta, ws_cut, out);
}

// Round 11
// 332.377 us; speedup vs baseline: 1.1442x; 1.1442x over previous
//
#include <hip/hip_runtime.h>
#include <math.h>
#include <stdint.h>

// Problem constants
#define BB    32
#define CIN   64
#define HH    32
#define WW    32
#define COUT  128
#define PP    1024      // HH*WW
#define OTILE 8         // output channels per block
#define PTILE 256       // pixels per block (4 waves x 64 px = 8 rows)
#define NPAD  12        // sorted theta list padded to 12 (pair-prefetch headroom)
#define TABN  160       // f-table knots
#define TROW  36        // tile row stride (34 cols + 2 slack)
#define TWSZ  148       // per-wave tile dwords (4*36 + dump + pad)
#define THCH  (CIN * OTILE * NPAD)   // 6144 floats per o-tile theta chunk

// Log2 domain: Z = (x - theta)*SCALEE. Table coord u = 8Z + 24 = x*MSC8 + thp,
// thp = 24 - theta*MSC8.
static constexpr float MSC8     = 153.88747102815611f;   // inv_denom*log2(e)*8
static constexpr float M2N      = 0.26359713811572677f;  // 2^-SBITS = e^-shift
static constexpr float OUTSCALE = 2.7025482032898827e-05f; // ALPHA*R*ln2^2
static constexpr float ZLO      = -3.0f;
static constexpr float TABH     = 0.125f;
static constexpr float IDXBIAS  = 24.0f;                 // -ZLO/h
static constexpr float CUTBIAS  = 4.0f;                  // 24 - 8*ZCUT, ZCUT = 2.5

// ---------------- P0: prescale, koff-stuff, sort desc, pad ----------------
// ws layout: chunk per o-tile, inside chunk [c][g][NPAD]:
//   ws[(o>>3)*THCH + c*(OTILE*NPAD) + (o&7)*NPAD + j]
__global__ __launch_bounds__(256) void sort_theta_kernel(
    const float* __restrict__ theta, float* __restrict__ ws)
{
    int gid = blockIdx.x * 256 + threadIdx.x;   // o*CIN + c (theta layout)
    if (gid >= COUT * CIN) return;
    int o = gid >> 6, c = gid & 63;
    const float* tg = theta + (size_t)gid * 9;
    float v[NPAD];
#pragma unroll
    for (int k = 0; k < 9; ++k) {
        float thp = fmaf(tg[k], -MSC8, IDXBIAS);
        int dy = k / 3, dx = k - 3 * dy;
        uint32_t koff = (uint32_t)(dy * TROW + dx);      // {0,1,2,36,37,38,72,73,74}
        v[k] = __uint_as_float((__float_as_uint(thp) & ~0x7Fu) | koff);
    }
    for (int i = 1; i < 9; ++i) {               // insertion sort DESCENDING
        float key = v[i];
        int j = i - 1;
        while (j >= 0 && v[j] < key) { v[j + 1] = v[j]; --j; }
        v[j + 1] = key;
    }
    float pad = __uint_as_float(__float_as_uint(-1e30f) & ~0x7Fu);  // inactive, koff=0
#pragma unroll
    for (int j = 9; j < NPAD; ++j) v[j] = pad;
    float* og = ws + (size_t)(o >> 3) * THCH + (size_t)c * (OTILE * NPAD) + (o & 7) * NPAD;
#pragma unroll
    for (int j = 0; j < NPAD; ++j) og[j] = v[j];
}

// ---------------- P1: per-(b, band, c) cut in thp units ----------------
__global__ __launch_bounds__(256) void bandcut_kernel(
    const float* __restrict__ x, float* __restrict__ bandcut)
{
    int t  = threadIdx.x;
    int bc = blockIdx.x;            // b*CIN + c
    const float4* xp = (const float4*)(x + (size_t)bc * PP);
    float4 v = xp[t];               // thread t: row t>>3, cols 4(t&7)..+3
    float m = fmaxf(fmaxf(v.x, v.y), fmaxf(v.z, v.w));
    m = fmaxf(m, __shfl_xor(m, 1));
    m = fmaxf(m, __shfl_xor(m, 2));
    m = fmaxf(m, __shfl_xor(m, 4));   // 8 threads of a row hold rowmax
    __shared__ float rmax[32];
    if ((t & 7) == 0) rmax[t >> 3] = m;
    __syncthreads();
    if (t < 16) {
        int r0 = max(2 * t - 1, 0), r3 = min(2 * t + 2, 31);
        float mm = rmax[r0];
        for (int r = r0 + 1; r <= r3; ++r) mm = fmaxf(mm, rmax[r]);
        mm = fmaxf(mm, 0.0f);         // zero-pad contributes xi = 0
        int b = bc >> 6, c = bc & 63;
        bandcut[((b * 16 + t) << 6) + c] = fmaf(mm, -MSC8, CUTBIAS);
    }
}

// ---------------- main kernel ----------------
__global__ __launch_bounds__(256) void nlconv_kernel(
    const float* __restrict__ x,        // [B, CIN, 32, 32]
    const float* __restrict__ wst,      // sorted thp chunks [ot][c][g][NPAD]
    const float* __restrict__ wcut,     // cutp [b][band][c]
    float* __restrict__ out)            // [B, COUT, 32, 32]
{
    __shared__ float  sth[THCH];        // this o-tile's theta lists, 24576 B
    __shared__ float  sxi[4 * TWSZ];    // per-wave 4x36 halo tiles + dump, 2368 B
    __shared__ float2 ftab[TABN];       // coefficient table (c0, c1), 1280 B

    const int t  = threadIdx.x;
    const int b  = blockIdx.x;
    const int pt = blockIdx.y;
    const int ot = blockIdx.z;
    const int w  = t >> 6;
    const int l  = t & 63;
    const int o0 = ot * OTILE;
    const int band = pt * 4 + w;
    const int rl = l >> 5, col = l & 31;

    // stage this o-tile's theta lists (contiguous chunk, float4)
    {
        const float4* src = (const float4*)(wst + (size_t)ot * THCH);
        float4* dst = (float4*)sth;
#pragma unroll
        for (int i = t; i < THCH / 4; i += PTILE) dst[i] = src[i];
    }

    // build the coefficient table in-kernel (fp32; err ~1e-5 f-units, negligible)
    if (t < TABN) {
        float Z0 = ZLO + TABH * (float)t;
        auto fe = [](float Z) {
            float E = exp2f(Z);
            float a = log2f(1.0f + E);
            float bq = log2f(fmaf(E, M2N, 1.0f));
            return a * a - bq * bq;
        };
        float y0 = fe(Z0), y1 = fe(Z0 + TABH);
        float c1 = y1 - y0;                       // per-u slope; i=158 segment
        ftab[t] = make_float2(fmaf(-(float)t, c1, y0), c1);  // extrapolates tail
    }

    // per-lane staging map: 3 entries e = l, l+64, l+128 over the 144-dword tile
    const int wbase = w * TWSZ;
    int   gofs[3];   // dword offset within a channel's 1024-px image
    float msc[3];    // MSC8 or 0 (halo/invalid)
    int   laddr[3];  // dword index into sxi
#pragma unroll
    for (int i = 0; i < 3; ++i) {
        int e  = l + 64 * i;
        bool valid = (e < 144);
        int ec = valid ? e : 144;           // dump slot for invalid third entries
        int r  = ec / TROW;
        int tc = ec - r * TROW;
        int grow = band * 2 - 1 + r;
        int gcol = tc - 1;
        bool inter = valid && (grow >= 0) && (grow < HH) && (gcol >= 0) && (gcol < WW) && (r < 4);
        gofs[i]  = (min(max(grow, 0), HH - 1) << 5) + min(max(gcol, 0), WW - 1);
        msc[i]   = inter ? MSC8 : 0.0f;
        laddr[i] = wbase + min(ec, TWSZ - 1);
    }

    // this wave's 64 channel cuts: lane c holds cutp[c]
    const float vcut = wcut[(size_t)((b * 16 + band) << 6) + l];

    // spread offsets for the ballot count, relative to a c-row of sth
    // sp1: 2 lanes/bank (free); sp2: 8-lane same-address broadcast (free)
    const int sp1 = (l >> 3) * NPAD + (l & 7);   // g = l>>3, j = l&7
    const int sp2 = (l & 7) * NPAD + 8;          // g = l&7,  j = 8

    const float* xc0 = x + (size_t)b * CIN * PP;
    const int xb = wbase + rl * TROW + col;      // body x base (dword)

    float acc[OTILE];
#pragma unroll
    for (int i = 0; i < OTILE; ++i) acc[i] = 0.0f;

    // prologue: xv(0) -> tile(0); xv <- c=1  (wave-private, no barrier needed)
    float xv[3];
#pragma unroll
    for (int i = 0; i < 3; ++i) xv[i] = xc0[gofs[i]] * msc[i];
#pragma unroll
    for (int i = 0; i < 3; ++i) sxi[laddr[i]] = xv[i];
#pragma unroll
    for (int i = 0; i < 3; ++i) xv[i] = xc0[PP + gofs[i]] * msc[i];

    __syncthreads();   // sth + ftab ready

    // c=0 spread values (LDS)
    float f1 = sth[sp1], f2 = sth[sp2];

    for (int c = 0; c < CIN; ++c) {
        const float cutp = __uint_as_float(
            (uint32_t)__builtin_amdgcn_readlane((int)__float_as_uint(vcut), c));
        unsigned long long mA = __ballot(f1 > cutp);
        unsigned long long mB = __ballot(f2 > cutp);

        // prefetch next c's spread values (LDS, cheap, in-order)
        {
            int nc = min(c + 1, CIN - 1) * (OTILE * NPAD);
            f1 = sth[nc + sp1];
            f2 = sth[nc + sp2];
        }

        const float* thc = sth + c * (OTILE * NPAD);

#pragma unroll
        for (int g = 0; g < 8; ++g) {
            int cnt = (int)__popcll(mA & (0xFFull << (8 * g)))
                    + (int)((mB >> g) & 1ull);
            int np = (cnt + 1) >> 1;           // pair iterations (<=5)
            asm volatile("" : "+s"(np));       // opaque: loop stays a real loop
            const float* gth = thc + g * NPAD;
            float2 pc = *(const float2*)gth;   // pair 0 (ds_read_b64, broadcast)
            float a = acc[g];
#pragma unroll 1
            for (int j = 0; j < np; ++j) {
                float2 pn = *(const float2*)(gth + 2 * j + 2);  // prefetch j+1 (<= floats 10,11)
                // body A: ~9 VALU + 2 LDS; i=158 segment extrapolates the tail
                {
                    int   ko = (int)(__float_as_uint(pc.x) & 0x7Fu);
                    float xa = sxi[xb + ko];                   // ds_read
                    float u  = fmaxf(xa + pc.x, 0.0f);         // pads -> u=0 -> tv~f(-3)~0
                    int   i  = min((int)u, TABN - 2);
                    float2 cf = ftab[i];                       // ds_read_b64 (c0, c1)
                    a = fmaf(cf.y, u, a) + cf.x;               // a += c0 + c1*u
                }
                // body B
                {
                    int   ko = (int)(__float_as_uint(pc.y) & 0x7Fu);
                    float xa = sxi[xb + ko];
                    float u  = fmaxf(xa + pc.y, 0.0f);
                    int   i  = min((int)u, TABN - 2);
                    float2 cf = ftab[i];
                    a = fmaf(cf.y, u, a) + cf.x;
                }
                pc = pn;
            }
            acc[g] = a;
        }

        // stage tile(c+1) from xv, then prefetch xv(c+2)
#pragma unroll
        for (int i = 0; i < 3; ++i) sxi[laddr[i]] = xv[i];
        {
            int c2 = min(c + 2, CIN - 1);
            const float* xcn = xc0 + (size_t)c2 * PP;
#pragma unroll
            for (int i = 0; i < 3; ++i) xv[i] = xcn[gofs[i]] * msc[i];
        }
    }

    float* ob = out + ((size_t)b * COUT + o0) * PP + pt * PTILE + t;
#pragma unroll
    for (int o = 0; o < OTILE; ++o) {
        float v = acc[o] * OUTSCALE;
        v = fminf(fmaxf(v, 0.0f), 9.0f);
        ob[(size_t)o * PP] = v;
    }
}

extern "C" void kernel_launch(void* const* d_in, const int* in_sizes, int n_in,
                              void* d_out, int out_size, void* d_ws, size_t ws_size,
                              hipStream_t stream) {
    const float* x     = (const float*)d_in[0];  // [32,64,32,32]
    const float* theta = (const float*)d_in[1];  // [128,64,3,3]
    float* out         = (float*)d_out;          // [32,128,32,32]

    float* ws_theta = (float*)d_ws;                               // 393,216 B
    float* ws_cut   = ws_theta + (size_t)16 * THCH;               // 131,072 B

    sort_theta_kernel<<<dim3((COUT * CIN + 255) / 256), dim3(256), 0, stream>>>(theta, ws_theta);
    bandcut_kernel<<<dim3(BB * CIN), dim3(256), 0, stream>>>(x, ws_cut);

    dim3 grid(BB, PP / PTILE, COUT / OTILE);     // 32 x 4 x 16 = 2048 blocks
    nlconv_kernel<<<grid, dim3(256), 0, stream>>>(x, ws_theta, ws_cut, out);
}